// Round 14
// baseline (200.185 us; speedup 1.0000x reference)
//
#include <hip/hip_runtime.h>
#include <hip/hip_bf16.h>

// B=2, S=2048, D=1024, H=16, HD=64.  out = proj(attn(qkv(x))), fp32 I/O,
// bf16 MFMA internally.
//
// R25 = R24 (best: 164.2us) with gemm_qkv's A operand moved out of LDS:
// each lane register-prefetches next iter's 4 A fragments (short8) directly
// from global/L2 (A = 8MB, L2-resident, reused 24x; fragments are 16-row x
// 64B segments - coalesced enough for L2).  B keeps the 3-buffer
// counted-vmcnt LDS pipeline (stage = 2 async16/thread).  Per-iter VMEM
// queue = 2 B-stage + 4 A-loads -> barrier wait vmcnt(6) drains exactly
// B-stage(t); compiler inserts A-fragment waits.  Halves qkv LDS traffic
// (1.18GB -> 0.59GB), drops LDS to 33.8KB -> 4 blocks/CU.  Bit-identical
// values.  prep/proj/attn6p = R24 verbatim.

typedef __attribute__((ext_vector_type(8))) short short8;
typedef __attribute__((ext_vector_type(4))) float float4v;

#define S_LEN 2048
#define NHEAD 16
#define HDIM  64
#define DMODEL 1024

__device__ __forceinline__ unsigned short f2bf(float f) {
    union { float f; unsigned u; } v; v.f = f;
    unsigned r = v.u + 0x7FFF + ((v.u >> 16) & 1);   // RNE
    return (unsigned short)(r >> 16);
}

__device__ __forceinline__ unsigned fbits_rn(float f) {  // bits+0x8000: RN pack
    union { float f; unsigned u; } v; v.f = f;
    return v.u + 0x8000u;
}

__device__ __forceinline__ void async16(const void* g, const void* l) {
    __builtin_amdgcn_global_load_lds(
        (const __attribute__((address_space(1))) unsigned int*)g,
        (__attribute__((address_space(3))) unsigned int*)l, 16, 0, 0);
}

// ---------------------------------------------------------------------------
// prep: blocks 0..1023 transpose both weight matrices (in[K][N] fp32 ->
// out[N][K] bf16); blocks 1024..5119 convert x fp32 -> bf16 (float4/thread).
// ---------------------------------------------------------------------------
__global__ __launch_bounds__(256) void prep_kernel(
    const float* __restrict__ x, unsigned short* __restrict__ x_bf,
    const float* __restrict__ Wqkv, const float* __restrict__ Wproj,
    unsigned short* __restrict__ outQ, unsigned short* __restrict__ outP)
{
    __shared__ float t[64][65];
    const int bx = blockIdx.x;
    const int tid = threadIdx.x;

    if (bx >= 1024) {
        // ---- f2bf part: 4096 blocks, 4 floats/thread ----
        const int i = (bx - 1024) * 256 + tid;
        float4 v = ((const float4*)x)[i];
        ushort4 o;
        o.x = f2bf(v.x); o.y = f2bf(v.y); o.z = f2bf(v.z); o.w = f2bf(v.w);
        ((ushort4*)x_bf)[i] = o;
        return;
    }

    // ---- transpose part: tb = bx in 0..1023 -> (bxl0 0..63, by 0..15) ----
    const int bxl0 = bx & 63, by = bx >> 6;
    const float* in; unsigned short* out; int N, bxl;
    if (bxl0 < 48) { in = Wqkv;  out = outQ; N = 3072; bxl = bxl0; }
    else           { in = Wproj; out = outP; N = 1024; bxl = bxl0 - 48; }
    const int K = 1024;
    const int kb = by * 64, nb = bxl * 64;
    const int r0 = tid >> 4, c0 = (tid & 15) * 4;
#pragma unroll
    for (int g = 0; g < 4; g++) {
        float4 v = *(const float4*)(in + (size_t)(kb + g * 16 + r0) * N + nb + c0);
        t[g * 16 + r0][c0 + 0] = v.x; t[g * 16 + r0][c0 + 1] = v.y;
        t[g * 16 + r0][c0 + 2] = v.z; t[g * 16 + r0][c0 + 3] = v.w;
    }
    __syncthreads();
#pragma unroll
    for (int g = 0; g < 4; g++) {
        int n = g * 16 + r0;
        ushort4 o;
        o.x = f2bf(t[c0 + 0][n]); o.y = f2bf(t[c0 + 1][n]);
        o.z = f2bf(t[c0 + 2][n]); o.w = f2bf(t[c0 + 3][n]);
        *(ushort4*)(out + (size_t)(nb + n) * K + kb + c0) = o;
    }
}

// ---------------------------------------------------------------------------
// QKV GEMM: C[M,3072] = A[M,1024]*Bt[3072,1024]^T + bias.  BK=32.
// A: register-direct from global/L2, 2-deep prefetch (afc/afn).
// B: 3-buffer counted-vmcnt LDS pipeline (Bbuf[b] at +b*4096 shorts).
// Barrier = s_waitcnt vmcnt(6) + raw s_barrier + sched_barrier(0).
// Epilogue: pair-packed b32 writes into 128x132 tile (aliases the bufs),
// then line-coalesced 16B stores: Q -> [bh][s][64], K -> Kp fragment-major,
// V -> Vp fragment-major (8 u16 gathers per piece).
// Vp semantics (R3-verified): piece (ch,nt,kk,lane=q*16+l), short j holds
//   key = (kk*2 + (j>>2))*16 + q*4 + (j&3),  hd = nt*16 + l.
// ---------------------------------------------------------------------------
#define QSCALE 0.18033688f   // 0.125 * log2(e), folded into Q

__global__ __launch_bounds__(256) void gemm_qkv_kernel(
    const unsigned short* __restrict__ A,
    const unsigned short* __restrict__ Bt,
    const float* __restrict__ bias,
    unsigned short* __restrict__ out_q,
    unsigned short* __restrict__ out_kp,
    unsigned short* __restrict__ out_vp,
    int M, int N, int K)
{
    __shared__ unsigned short smem[16896];   // 33.8KB: 3 B-bufs + epi tile

    const int tid  = threadIdx.x;
    const int lane = tid & 63;
    const int wave = tid >> 6;
    const int quad = lane >> 4;
    const int l16  = lane & 15;

    const int m0 = blockIdx.y * 128;
    const int n0 = blockIdx.x * 128;
    const int wm = (wave >> 1) * 64;
    const int wn = (wave & 1) * 64;

    float4v acc[4][4];
#pragma unroll
    for (int i = 0; i < 4; i++)
#pragma unroll
        for (int j = 0; j < 4; j++) acc[i][j] = (float4v){0.f, 0.f, 0.f, 0.f};

    const int NT = 32;                       // K / 32
#define QKV_STAGE_B(tt, bufi)                                                 \
    {                                                                         \
        const int k1 = (tt) * 32;                                             \
        unsigned short* Bb = smem + (bufi) * 4096;                            \
        _Pragma("unroll")                                                     \
        for (int rd = 0; rd < 2; rd++) {                                      \
            const int p = rd * 256 + tid;                                     \
            async16(Bt + (size_t)(n0 + (p >> 2)) * K + k1 + (p & 3) * 8,      \
                    (const char*)Bb + p * 16);                                \
        }                                                                     \
    }

    // per-lane A fragment base pointers (row = m0+wm+mt*16+l16, col quad*8)
    const unsigned short* ap[4];
#pragma unroll
    for (int mt = 0; mt < 4; mt++)
        ap[mt] = A + (size_t)(m0 + wm + mt * 16 + l16) * K + quad * 8;

    // prologue: stage B tiles 0,1; load A fragments for tile 0
    QKV_STAGE_B(0, 0);
    QKV_STAGE_B(1, 1);
    short8 afc[4], afn[4];
#pragma unroll
    for (int mt = 0; mt < 4; mt++)
        afc[mt] = *(const short8*)(ap[mt]);

    int rb = 0;                              // read-buffer = t % 3
    for (int t = 0; t < NT; t++) {
        // B-stage(t) is the oldest VMEM entry; 6 = stage(t+1)[2] + af(t)[4]
        if (t + 1 < NT) asm volatile("s_waitcnt vmcnt(6)" ::: "memory");
        else            asm volatile("s_waitcnt vmcnt(0)" ::: "memory");
        __builtin_amdgcn_s_barrier();
        __builtin_amdgcn_sched_barrier(0);

        if (t + 2 < NT) {
            const int sbi = (rb + 2 >= 3) ? rb - 1 : rb + 2;
            QKV_STAGE_B(t + 2, sbi);
        }
        if (t + 1 < NT) {
            const int k1 = (t + 1) * 32;
#pragma unroll
            for (int mt = 0; mt < 4; mt++)
                afn[mt] = *(const short8*)(ap[mt] + k1);
        }

        const unsigned short* Br = smem + rb * 4096;
        short8 bf[4];
#pragma unroll
        for (int nt = 0; nt < 4; nt++)
            bf[nt] = *(const short8*)(Br + (wn + nt * 16 + l16) * 32 + quad * 8);
#pragma unroll
        for (int mt = 0; mt < 4; mt++)
#pragma unroll
            for (int nt = 0; nt < 4; nt++)
                acc[mt][nt] = __builtin_amdgcn_mfma_f32_16x16x32_bf16(
                    afc[mt], bf[nt], acc[mt][nt], 0, 0, 0);

#pragma unroll
        for (int mt = 0; mt < 4; mt++) afc[mt] = afn[mt];
        rb = (rb + 1 == 3) ? 0 : rb + 1;
    }
#undef QKV_STAGE_B

    // ---- epilogue: pair-packed b32 writes (stride 66 dwords) ----
    __syncthreads();   // all waves done reading bufs before tile overwrite
#pragma unroll
    for (int nt = 0; nt < 4; nt++) {
        const int col = n0 + wn + nt * 16 + l16;
        const float sc = ((col >> 10) == 0) ? QSCALE : 1.0f;
        const float bia = bias[col] * sc;
        const int cold = (wn + nt * 16 + l16) >> 1;
#pragma unroll
        for (int mt = 0; mt < 4; mt++)
#pragma unroll
            for (int r = 0; r < 4; r++) {
                unsigned fb = fbits_rn(acc[mt][nt][r] * sc + bia);
                unsigned fbp = (unsigned)__shfl_xor((int)fb, 1, 64);
                unsigned pd = (l16 & 1)
                    ? __builtin_amdgcn_perm(fb, fbp, 0x07060302)
                    : __builtin_amdgcn_perm(fbp, fb, 0x07060302);
                const int rowl = wm + mt * 16 + quad * 4 + r;
                *((unsigned*)smem + rowl * 66 + cold) = pd;
            }
    }
    __syncthreads();

    // ---- store phase: 16B pieces.  Q: [bh][s][64]; K: Kp fragment-major;
    //      V: Vp fragment-major (gathered). ----
#pragma unroll
    for (int ps = 0; ps < 8; ps++) {
        const int row = ps * 16 + (tid >> 4);
        const int pc  = tid & 15;
        const int col0 = pc * 8;
        const int cb = n0 + (col0 >> 6) * 64;
        const int part = cb >> 10;
        const int hh = (cb & 1023) >> 6;           // head
        const int gr = m0 + row;
        const int b = gr >> 11, s = gr & 2047;
        const size_t bhI = (size_t)(b * NHEAD + hh);
        if (part == 2) {
            // Vp piece: (cl=ps>>2, nt=ps&3, kk=(pc>>2)&1, q=pc&3, l=tid>>4)
            const int l2  = tid >> 4;
            const int q2  = pc & 3;
            const int kk2 = (pc >> 2) & 1;
            const int nt2 = ps & 3;
            const int colb = (pc >> 3) * 64 + nt2 * 16 + l2;
            const int rowb = (ps >> 2) * 64;
            union { unsigned short u[8]; uint4 q; } wv;
#pragma unroll
            for (int j = 0; j < 8; j++) {
                const int key = (kk2 * 2 + (j >> 2)) * 16 + q2 * 4 + (j & 3);
                wv.u[j] = smem[(rowb + key) * 132 + colb];
            }
            unsigned short* po = out_vp
                + ((((bhI * 32 + (s >> 6)) * 4 + nt2) * 2 + kk2) * 64
                   + q2 * 16 + l2) * 8;
            *(uint4*)po = wv.q;
        } else {
            const unsigned short* pl = smem + row * 132 + col0;
            uint2 a = *(const uint2*)(pl);
            uint2 bb = *(const uint2*)(pl + 4);
            uint4 w; w.x = a.x; w.y = a.y; w.z = bb.x; w.w = bb.y;
            unsigned short* po;
            if (part == 1) {
                // Kp[bh][chunk=s>>6][kt=(s>>4)&3][h][lane=q*16+(s&15)][8]
                const int hd = col0 & 63;
                const int h = hd >> 5, q = (hd >> 3) & 3;
                po = out_kp + ((((bhI * 32 + (s >> 6)) * 4 + ((s >> 4) & 3)) * 2
                                + h) * 64 + q * 16 + (s & 15)) * 8;
            } else {
                po = out_q + (bhI * S_LEN + s) * HDIM + (col0 & 63);
            }
            *(uint4*)po = w;
        }
    }
}

// ---------------------------------------------------------------------------
// proj GEMM: out[M,1024] fp32 = ctx[M,1024]*Wt^T + bias.  64x128 tile,
// BK=32, 3-buffer counted-vmcnt pipeline (Abuf[b] at +b*2048, Bbuf[b] at
// +6144+b*4096 = 36KB).  Stage = 3 async16/thread -> vmcnt(3).
// ---------------------------------------------------------------------------
__global__ __launch_bounds__(256) void gemm_proj_kernel(
    const unsigned short* __restrict__ A,
    const unsigned short* __restrict__ Bt,
    const float* __restrict__ bias,
    float* __restrict__ out_f,
    int M, int N, int K)
{
    __shared__ unsigned short smem[18432];   // 36KB: 3x(A 2048 + B 4096)

    const int tid  = threadIdx.x;
    const int lane = tid & 63;
    const int wave = tid >> 6;
    const int quad = lane >> 4;
    const int l16  = lane & 15;

    const int m0 = blockIdx.y * 64;
    const int n0 = blockIdx.x * 128;
    const int wm = (wave >> 1) * 32;
    const int wn = (wave & 1) * 64;

    float4v acc[2][4];
#pragma unroll
    for (int i = 0; i < 2; i++)
#pragma unroll
        for (int j = 0; j < 4; j++) acc[i][j] = (float4v){0.f, 0.f, 0.f, 0.f};

    const int NT = 32;                       // K / 32
#define PROJ_STAGE(tt, bufi)                                                  \
    {                                                                         \
        const int k1 = (tt) * 32;                                             \
        unsigned short* Ab = smem + (bufi) * 2048;                            \
        unsigned short* Bb = smem + 6144 + (bufi) * 4096;                     \
        async16(A + (size_t)(m0 + (tid >> 2)) * K + k1 + (tid & 3) * 8,       \
                (const char*)Ab + tid * 16);                                  \
        _Pragma("unroll")                                                     \
        for (int rd = 0; rd < 2; rd++) {                                      \
            const int p = rd * 256 + tid;                                     \
            async16(Bt + (size_t)(n0 + (p >> 2)) * K + k1 + (p & 3) * 8,      \
                    (const char*)Bb + p * 16);                                \
        }                                                                     \
    }

    PROJ_STAGE(0, 0);
    PROJ_STAGE(1, 1);

    int rb = 0;
    for (int t = 0; t < NT; t++) {
        if (t + 1 < NT) asm volatile("s_waitcnt vmcnt(3)" ::: "memory");
        else            asm volatile("s_waitcnt vmcnt(0)" ::: "memory");
        __builtin_amdgcn_s_barrier();
        __builtin_amdgcn_sched_barrier(0);

        if (t + 2 < NT) {
            const int sbi = (rb + 2 >= 3) ? rb - 1 : rb + 2;
            PROJ_STAGE(t + 2, sbi);
        }

        const unsigned short* Ar = smem + rb * 2048;
        const unsigned short* Br = smem + 6144 + rb * 4096;
        short8 af[2], bf[4];
#pragma unroll
        for (int mt = 0; mt < 2; mt++)
            af[mt] = *(const short8*)(Ar + (wm + mt * 16 + l16) * 32 + quad * 8);
#pragma unroll
        for (int nt = 0; nt < 4; nt++)
            bf[nt] = *(const short8*)(Br + (wn + nt * 16 + l16) * 32 + quad * 8);
#pragma unroll
        for (int mt = 0; mt < 2; mt++)
#pragma unroll
            for (int nt = 0; nt < 4; nt++)
                acc[mt][nt] = __builtin_amdgcn_mfma_f32_16x16x32_bf16(
                    af[mt], bf[nt], acc[mt][nt], 0, 0, 0);

        rb = (rb + 1 == 3) ? 0 : rb + 1;
    }
#undef PROJ_STAGE

#pragma unroll
    for (int nt = 0; nt < 4; nt++) {
        const int col = n0 + wn + nt * 16 + l16;
        const float bia = bias[col];
#pragma unroll
        for (int mt = 0; mt < 2; mt++) {
            const int rowb = m0 + wm + mt * 16 + quad * 4;
#pragma unroll
            for (int r = 0; r < 4; r++)
                out_f[(size_t)(rowb + r) * N + col] = acc[mt][nt][r] + bia;
        }
    }
}

// ---------------------------------------------------------------------------
// Attention v6p (R20): 3-buffer counted-vmcnt staging.  1024 blocks x 256
// thr (4 waves, 16 q each).  Prologue stages chunks 0,1; iteration c issues
// stage(c+2) into buf (c+2)%3; barrier = s_waitcnt vmcnt(4) + raw s_barrier
// + sched_barrier(0).  bh = bx&31 pins heads to XCDs; qb = 31-(bx>>5)
// dispatches heavy first.
// ---------------------------------------------------------------------------
__global__ __launch_bounds__(256) void attn6p_kernel(
    const unsigned short* __restrict__ Q,    // [bh][s][64] pre-scaled
    const unsigned short* __restrict__ Kp,   // [bh][32][4][2][64][8]
    const unsigned short* __restrict__ Vp,   // [bh][32][4][2][64][8]
    unsigned short* __restrict__ ctx)        // [B, S, H*64]
{
    __shared__ unsigned short lds[3][8192];  // [buf][K 0..4095 | V 4096..8191]

    const int tid  = threadIdx.x;
    const int lane = tid & 63;
    const int wave = tid >> 6;
    const int quad = lane >> 4;
    const int l16  = lane & 15;

    const int bx = blockIdx.x;
    const int bh = bx & 31;
    const int qb = 31 - (bx >> 5);
    const int q0 = qb * 64 + wave * 16;
    const int nch = qb + 1;

    const size_t baseQ = (size_t)bh * S_LEN * HDIM;
    const unsigned short* kb_ = Kp + (size_t)bh * 32 * 4096;
    const unsigned short* vb_ = Vp + (size_t)bh * 32 * 4096;

    short8 qf[2];
#pragma unroll
    for (int h = 0; h < 2; h++)
        qf[h] = *(const short8*)(Q + baseQ + (size_t)(q0 + l16) * HDIM
                                 + h * 32 + quad * 8);

    float4v o[4];
#pragma unroll
    for (int nt = 0; nt < 4; nt++) o[nt] = (float4v){0.f, 0.f, 0.f, 0.f};
    float lsa[4] = {0.f, 0.f, 0.f, 0.f};

    // prologue: stage chunks 0 and 1 (4 async16 each per thread)
    {
        unsigned short* sb = &lds[0][0];
        async16(kb_ + tid * 8,        sb + wave * 512);
        async16(kb_ + 2048 + tid * 8, sb + 2048 + wave * 512);
        async16(vb_ + tid * 8,        sb + 4096 + wave * 512);
        async16(vb_ + 2048 + tid * 8, sb + 6144 + wave * 512);
    }
    if (nch > 1) {
        const unsigned short* kc = kb_ + 4096;
        const unsigned short* vc = vb_ + 4096;
        unsigned short* sb = &lds[1][0];
        async16(kc + tid * 8,        sb + wave * 512);
        async16(kc + 2048 + tid * 8, sb + 2048 + wave * 512);
        async16(vc + tid * 8,        sb + 4096 + wave * 512);
        async16(vc + 2048 + tid * 8, sb + 6144 + wave * 512);
    }

    int rb = 0;    // read-buffer index = c % 3
    for (int c = 0; c < nch; c++) {
        // stage(c) must be landed for ALL waves; stage(c+1) stays in flight.
        if (c + 1 < nch) asm volatile("s_waitcnt vmcnt(4)" ::: "memory");
        else             asm volatile("s_waitcnt vmcnt(0)" ::: "memory");
        __builtin_amdgcn_s_barrier();
        __builtin_amdgcn_sched_barrier(0);

        const unsigned short* lb = &lds[rb][0];

        // K fragments: linear conflict-free ds_read_b128
        short8 kf[4][2];
#pragma unroll
        for (int kt = 0; kt < 4; kt++)
#pragma unroll
            for (int h = 0; h < 2; h++)
                kf[kt][h] = *(const short8*)(lb + ((kt * 2 + h) * 64 + lane) * 8);

        // stage chunk c+2 into buf (c+2)%3 (lands by barrier of c+2)
        if (c + 2 < nch) {
            const int sbi = (rb + 2 >= 3) ? rb - 1 : rb + 2;
            const unsigned short* kc = kb_ + (size_t)(c + 2) * 4096;
            const unsigned short* vc = vb_ + (size_t)(c + 2) * 4096;
            unsigned short* sb = &lds[sbi][0];
            async16(kc + tid * 8,        sb + wave * 512);
            async16(kc + 2048 + tid * 8, sb + 2048 + wave * 512);
            async16(vc + tid * 8,        sb + 4096 + wave * 512);
            async16(vc + 2048 + tid * 8, sb + 6144 + wave * 512);
        }

        float4v st[4];
#pragma unroll
        for (int kt = 0; kt < 4; kt++) {
            st[kt] = __builtin_amdgcn_mfma_f32_16x16x32_bf16(
                kf[kt][0], qf[0], (float4v){0.f, 0.f, 0.f, 0.f}, 0, 0, 0);
            st[kt] = __builtin_amdgcn_mfma_f32_16x16x32_bf16(
                kf[kt][1], qf[1], st[kt], 0, 0, 0);
        }

        // V fragments issue while the softmax VALU below runs
        short8 vf[4][2];
#pragma unroll
        for (int nt = 0; nt < 4; nt++)
#pragma unroll
            for (int kk = 0; kk < 2; kk++)
                vf[nt][kk] = *(const short8*)(lb + 4096
                                              + ((nt * 2 + kk) * 64 + lane) * 8);

        const bool lastc = (c == nch - 1);
        const int kb0 = c * 64;
        const int qpos = q0 + l16;
        float p[4][4];
#pragma unroll
        for (int kt = 0; kt < 4; kt++)
#pragma unroll
            for (int r = 0; r < 4; r++) {
                float x = st[kt][r];
                if (lastc) {
                    int kpos = kb0 + kt * 16 + quad * 4 + r;
                    x = (kpos <= qpos) ? x : -1e30f;
                }
                p[kt][r] = __builtin_amdgcn_exp2f(x);
                lsa[kt] += p[kt][r];     // 4 parallel chains
            }

        unsigned pk[4][2];
#pragma unroll
        for (int kt = 0; kt < 4; kt++)
#pragma unroll
            for (int j = 0; j < 2; j++)
                pk[kt][j] = __builtin_amdgcn_perm(
                    fbits_rn(p[kt][2 * j + 1]), fbits_rn(p[kt][2 * j]),
                    0x07060302);
        union { unsigned u[4]; short8 s; } pf[2];
#pragma unroll
        for (int kk = 0; kk < 2; kk++)
#pragma unroll
            for (int pp = 0; pp < 4; pp++)
                pf[kk].u[pp] = pk[kk * 2 + (pp >> 1)][pp & 1];

#pragma unroll
        for (int nt = 0; nt < 4; nt++) {
            o[nt] = __builtin_amdgcn_mfma_f32_16x16x32_bf16(
                pf[0].s, vf[nt][0], o[nt], 0, 0, 0);
            o[nt] = __builtin_amdgcn_mfma_f32_16x16x32_bf16(
                pf[1].s, vf[nt][1], o[nt], 0, 0, 0);
        }

        rb = (rb + 1 == 3) ? 0 : rb + 1;
    }

    float l = (lsa[0] + lsa[1]) + (lsa[2] + lsa[3]);
    l += __shfl_xor(l, 16, 64);
    l += __shfl_xor(l, 32, 64);
    const float linv = 1.f / l;
    float lr[4];
#pragma unroll
    for (int r = 0; r < 4; r++) lr[r] = __shfl(linv, quad * 4 + r, 64);

    const int b = bh >> 4, h = bh & 15;
#pragma unroll
    for (int r = 0; r < 4; r++) {
        const int s = q0 + quad * 4 + r;
        const size_t off = ((size_t)(b * S_LEN + s)) * DMODEL + h * HDIM;
#pragma unroll
        for (int nt = 0; nt < 4; nt++)
            ctx[off + nt * 16 + l16] = f2bf(o[nt][r] * lr[r]);
    }
}

extern "C" void kernel_launch(void* const* d_in, const int* in_sizes, int n_in,
                              void* d_out, int out_size, void* d_ws, size_t ws_size,
                              hipStream_t stream) {
    const float* x     = (const float*)d_in[0];
    const float* Wqkv  = (const float*)d_in[1];
    const float* bqkv  = (const float*)d_in[2];
    const float* Wproj = (const float*)d_in[3];
    const float* bproj = (const float*)d_in[4];
    float* out = (float*)d_out;

    const int M  = 2 * S_LEN;     // 4096
    const int N1 = 3 * DMODEL;    // 3072
    const int K  = DMODEL;        // 1024

    unsigned short* x_bf    = (unsigned short*)d_ws;
    unsigned short* wqkv_t  = x_bf   + (size_t)M * K;
    unsigned short* wproj_t = wqkv_t + (size_t)K * N1;
    unsigned short* q_bf    = wproj_t + (size_t)K * DMODEL;
    unsigned short* kp_bf   = q_bf   + (size_t)M * DMODEL;
    unsigned short* vp_bf   = kp_bf  + (size_t)M * DMODEL;  // Vp fragment-major
    unsigned short* ctx_bf  = vp_bf  + (size_t)M * DMODEL;

    prep_kernel<<<5120, 256, 0, stream>>>(x, x_bf, Wqkv, Wproj,
                                          wqkv_t, wproj_t);

    dim3 g1(N1 / 128, M / 128);   // 24 x 32
    gemm_qkv_kernel<<<g1, 256, 0, stream>>>(x_bf, wqkv_t, bqkv,
                                            q_bf, kp_bf, vp_bf, M, N1, K);

    attn6p_kernel<<<1024, 256, 0, stream>>>(q_bf, kp_bf, vp_bf, ctx_bf);

    dim3 g3(DMODEL / 128, M / 64);   // 8 x 64
    gemm_proj_kernel<<<g3, 256, 0, stream>>>(ctx_bf, wproj_t, bproj, out,
                                             M, DMODEL, K);
}

// Round 15
// 163.867 us; speedup vs baseline: 1.2216x; 1.2216x over previous
//
#include <hip/hip_runtime.h>
#include <hip/hip_bf16.h>

// B=2, S=2048, D=1024, H=16, HD=64.  out = proj(attn(qkv(x))), fp32 I/O,
// bf16 MFMA internally.
//
// R26 = R24 (best: 164.2us) + XCD-aware block swizzle on both GEMMs.
// R25's A-register-direct REVERTED (79us: per-lane row-gather = 16 scattered
// 64B L2 transactions/load + VGPR 72->88 serialized the loop).
// R24's qkv FETCH=37MB vs 14MB ideal (2.6x over-fetch): all 768 blocks are
// co-resident round-robin across 8 XCDs -> scattered tiles, no panel stays
// in the 4MB per-XCD L2.  Swizzle wgid=(orig%8)*chunk+orig/8 (768%8==0,
// bijective) gives each XCD 4 complete tile-rows: A working set 1MB
// L2-resident (reused 24x), B streams via L3.  Same for proj (512%8==0).

typedef __attribute__((ext_vector_type(8))) short short8;
typedef __attribute__((ext_vector_type(4))) float float4v;

#define S_LEN 2048
#define NHEAD 16
#define HDIM  64
#define DMODEL 1024

__device__ __forceinline__ unsigned short f2bf(float f) {
    union { float f; unsigned u; } v; v.f = f;
    unsigned r = v.u + 0x7FFF + ((v.u >> 16) & 1);   // RNE
    return (unsigned short)(r >> 16);
}

__device__ __forceinline__ unsigned fbits_rn(float f) {  // bits+0x8000: RN pack
    union { float f; unsigned u; } v; v.f = f;
    return v.u + 0x8000u;
}

__device__ __forceinline__ void async16(const void* g, const void* l) {
    __builtin_amdgcn_global_load_lds(
        (const __attribute__((address_space(1))) unsigned int*)g,
        (__attribute__((address_space(3))) unsigned int*)l, 16, 0, 0);
}

// ---------------------------------------------------------------------------
// prep: blocks 0..1023 transpose both weight matrices (in[K][N] fp32 ->
// out[N][K] bf16); blocks 1024..5119 convert x fp32 -> bf16 (float4/thread).
// ---------------------------------------------------------------------------
__global__ __launch_bounds__(256) void prep_kernel(
    const float* __restrict__ x, unsigned short* __restrict__ x_bf,
    const float* __restrict__ Wqkv, const float* __restrict__ Wproj,
    unsigned short* __restrict__ outQ, unsigned short* __restrict__ outP)
{
    __shared__ float t[64][65];
    const int bx = blockIdx.x;
    const int tid = threadIdx.x;

    if (bx >= 1024) {
        // ---- f2bf part: 4096 blocks, 4 floats/thread ----
        const int i = (bx - 1024) * 256 + tid;
        float4 v = ((const float4*)x)[i];
        ushort4 o;
        o.x = f2bf(v.x); o.y = f2bf(v.y); o.z = f2bf(v.z); o.w = f2bf(v.w);
        ((ushort4*)x_bf)[i] = o;
        return;
    }

    // ---- transpose part: tb = bx in 0..1023 -> (bxl0 0..63, by 0..15) ----
    const int bxl0 = bx & 63, by = bx >> 6;
    const float* in; unsigned short* out; int N, bxl;
    if (bxl0 < 48) { in = Wqkv;  out = outQ; N = 3072; bxl = bxl0; }
    else           { in = Wproj; out = outP; N = 1024; bxl = bxl0 - 48; }
    const int K = 1024;
    const int kb = by * 64, nb = bxl * 64;
    const int r0 = tid >> 4, c0 = (tid & 15) * 4;
#pragma unroll
    for (int g = 0; g < 4; g++) {
        float4 v = *(const float4*)(in + (size_t)(kb + g * 16 + r0) * N + nb + c0);
        t[g * 16 + r0][c0 + 0] = v.x; t[g * 16 + r0][c0 + 1] = v.y;
        t[g * 16 + r0][c0 + 2] = v.z; t[g * 16 + r0][c0 + 3] = v.w;
    }
    __syncthreads();
#pragma unroll
    for (int g = 0; g < 4; g++) {
        int n = g * 16 + r0;
        ushort4 o;
        o.x = f2bf(t[c0 + 0][n]); o.y = f2bf(t[c0 + 1][n]);
        o.z = f2bf(t[c0 + 2][n]); o.w = f2bf(t[c0 + 3][n]);
        *(ushort4*)(out + (size_t)(nb + n) * K + kb + c0) = o;
    }
}

// ---------------------------------------------------------------------------
// QKV GEMM: C[M,3072] = A[M,1024]*Bt[3072,1024]^T + bias.  BK=32, 3-buffer
// counted-vmcnt pipeline (Abuf[b] at +b*4096, Bbuf[b] at +12288+b*4096).
// XCD-swizzled tile mapping (768 blocks, 96/XCD = 4 full tile-rows).
// Epilogue: pair-packed b32 writes into 128x132 tile (aliases the bufs),
// then line-coalesced 16B stores: Q -> [bh][s][64], K -> Kp fragment-major,
// V -> Vp fragment-major (8 u16 gathers per piece).
// Vp semantics (R3-verified): piece (ch,nt,kk,lane=q*16+l), short j holds
//   key = (kk*2 + (j>>2))*16 + q*4 + (j&3),  hd = nt*16 + l.
// ---------------------------------------------------------------------------
#define QSCALE 0.18033688f   // 0.125 * log2(e), folded into Q

__global__ __launch_bounds__(256) void gemm_qkv_kernel(
    const unsigned short* __restrict__ A,
    const unsigned short* __restrict__ Bt,
    const float* __restrict__ bias,
    unsigned short* __restrict__ out_q,
    unsigned short* __restrict__ out_kp,
    unsigned short* __restrict__ out_vp,
    int M, int N, int K)
{
    __shared__ unsigned short smem[24576];   // 48KB: 3x(A 4096 + B 4096)

    const int tid  = threadIdx.x;
    const int lane = tid & 63;
    const int wave = tid >> 6;
    const int quad = lane >> 4;
    const int l16  = lane & 15;

    // XCD-aware bijective swizzle: 768 blocks, chunk = 96 per XCD.
    const int GX = 24;                       // gridDim.x
    const int orig = blockIdx.y * GX + blockIdx.x;
    const int swz  = (orig & 7) * 96 + (orig >> 3);
    const int m0 = (swz / GX) * 128;
    const int n0 = (swz % GX) * 128;
    const int wm = (wave >> 1) * 64;
    const int wn = (wave & 1) * 64;

    float4v acc[4][4];
#pragma unroll
    for (int i = 0; i < 4; i++)
#pragma unroll
        for (int j = 0; j < 4; j++) acc[i][j] = (float4v){0.f, 0.f, 0.f, 0.f};

    const int NT = 32;                       // K / 32
#define QKV_STAGE(tt, bufi)                                                   \
    {                                                                         \
        const int k1 = (tt) * 32;                                             \
        unsigned short* Ab = smem + (bufi) * 4096;                            \
        unsigned short* Bb = smem + 12288 + (bufi) * 4096;                    \
        _Pragma("unroll")                                                     \
        for (int rd = 0; rd < 2; rd++) {                                      \
            const int p = rd * 256 + tid;                                     \
            async16(A  + (size_t)(m0 + (p >> 2)) * K + k1 + (p & 3) * 8,      \
                    (const char*)Ab + p * 16);                                \
            async16(Bt + (size_t)(n0 + (p >> 2)) * K + k1 + (p & 3) * 8,      \
                    (const char*)Bb + p * 16);                                \
        }                                                                     \
    }

    QKV_STAGE(0, 0);
    QKV_STAGE(1, 1);

    int rb = 0;                              // read-buffer = t % 3
    for (int t = 0; t < NT; t++) {
        if (t + 1 < NT) asm volatile("s_waitcnt vmcnt(4)" ::: "memory");
        else            asm volatile("s_waitcnt vmcnt(0)" ::: "memory");
        __builtin_amdgcn_s_barrier();
        __builtin_amdgcn_sched_barrier(0);

        if (t + 2 < NT) {
            const int sbi = (rb + 2 >= 3) ? rb - 1 : rb + 2;
            QKV_STAGE(t + 2, sbi);
        }

        const unsigned short* Ar = smem + rb * 4096;
        const unsigned short* Br = smem + 12288 + rb * 4096;
        short8 af[4], bf[4];
#pragma unroll
        for (int mt = 0; mt < 4; mt++)
            af[mt] = *(const short8*)(Ar + (wm + mt * 16 + l16) * 32 + quad * 8);
#pragma unroll
        for (int nt = 0; nt < 4; nt++)
            bf[nt] = *(const short8*)(Br + (wn + nt * 16 + l16) * 32 + quad * 8);
#pragma unroll
        for (int mt = 0; mt < 4; mt++)
#pragma unroll
            for (int nt = 0; nt < 4; nt++)
                acc[mt][nt] = __builtin_amdgcn_mfma_f32_16x16x32_bf16(
                    af[mt], bf[nt], acc[mt][nt], 0, 0, 0);

        rb = (rb + 1 == 3) ? 0 : rb + 1;
    }
#undef QKV_STAGE

    // ---- epilogue: pair-packed b32 writes (stride 66 dwords) ----
    __syncthreads();   // all waves done reading bufs before tile overwrite
#pragma unroll
    for (int nt = 0; nt < 4; nt++) {
        const int col = n0 + wn + nt * 16 + l16;
        const float sc = ((col >> 10) == 0) ? QSCALE : 1.0f;
        const float bia = bias[col] * sc;
        const int cold = (wn + nt * 16 + l16) >> 1;
#pragma unroll
        for (int mt = 0; mt < 4; mt++)
#pragma unroll
            for (int r = 0; r < 4; r++) {
                unsigned fb = fbits_rn(acc[mt][nt][r] * sc + bia);
                unsigned fbp = (unsigned)__shfl_xor((int)fb, 1, 64);
                unsigned pd = (l16 & 1)
                    ? __builtin_amdgcn_perm(fb, fbp, 0x07060302)
                    : __builtin_amdgcn_perm(fbp, fb, 0x07060302);
                const int rowl = wm + mt * 16 + quad * 4 + r;
                *((unsigned*)smem + rowl * 66 + cold) = pd;
            }
    }
    __syncthreads();

    // ---- store phase: 16B pieces.  Q: [bh][s][64]; K: Kp fragment-major;
    //      V: Vp fragment-major (gathered). ----
#pragma unroll
    for (int ps = 0; ps < 8; ps++) {
        const int row = ps * 16 + (tid >> 4);
        const int pc  = tid & 15;
        const int col0 = pc * 8;
        const int cb = n0 + (col0 >> 6) * 64;
        const int part = cb >> 10;
        const int hh = (cb & 1023) >> 6;           // head
        const int gr = m0 + row;
        const int b = gr >> 11, s = gr & 2047;
        const size_t bhI = (size_t)(b * NHEAD + hh);
        if (part == 2) {
            // Vp piece: (cl=ps>>2, nt=ps&3, kk=(pc>>2)&1, q=pc&3, l=tid>>4)
            const int l2  = tid >> 4;
            const int q2  = pc & 3;
            const int kk2 = (pc >> 2) & 1;
            const int nt2 = ps & 3;
            const int colb = (pc >> 3) * 64 + nt2 * 16 + l2;
            const int rowb = (ps >> 2) * 64;
            union { unsigned short u[8]; uint4 q; } wv;
#pragma unroll
            for (int j = 0; j < 8; j++) {
                const int key = (kk2 * 2 + (j >> 2)) * 16 + q2 * 4 + (j & 3);
                wv.u[j] = smem[(rowb + key) * 132 + colb];
            }
            unsigned short* po = out_vp
                + ((((bhI * 32 + (s >> 6)) * 4 + nt2) * 2 + kk2) * 64
                   + q2 * 16 + l2) * 8;
            *(uint4*)po = wv.q;
        } else {
            const unsigned short* pl = smem + row * 132 + col0;
            uint2 a = *(const uint2*)(pl);
            uint2 bb = *(const uint2*)(pl + 4);
            uint4 w; w.x = a.x; w.y = a.y; w.z = bb.x; w.w = bb.y;
            unsigned short* po;
            if (part == 1) {
                // Kp[bh][chunk=s>>6][kt=(s>>4)&3][h][lane=q*16+(s&15)][8]
                const int hd = col0 & 63;
                const int h = hd >> 5, q = (hd >> 3) & 3;
                po = out_kp + ((((bhI * 32 + (s >> 6)) * 4 + ((s >> 4) & 3)) * 2
                                + h) * 64 + q * 16 + (s & 15)) * 8;
            } else {
                po = out_q + (bhI * S_LEN + s) * HDIM + (col0 & 63);
            }
            *(uint4*)po = w;
        }
    }
}

// ---------------------------------------------------------------------------
// proj GEMM: out[M,1024] fp32 = ctx[M,1024]*Wt^T + bias.  64x128 tile,
// BK=32, 3-buffer counted-vmcnt pipeline (Abuf[b] at +b*2048, Bbuf[b] at
// +6144+b*4096 = 36KB).  Stage = 3 async16/thread -> vmcnt(3).
// XCD-swizzled tile mapping (512 blocks, 64/XCD = 8 full tile-rows).
// ---------------------------------------------------------------------------
__global__ __launch_bounds__(256) void gemm_proj_kernel(
    const unsigned short* __restrict__ A,
    const unsigned short* __restrict__ Bt,
    const float* __restrict__ bias,
    float* __restrict__ out_f,
    int M, int N, int K)
{
    __shared__ unsigned short smem[18432];   // 36KB: 3x(A 2048 + B 4096)

    const int tid  = threadIdx.x;
    const int lane = tid & 63;
    const int wave = tid >> 6;
    const int quad = lane >> 4;
    const int l16  = lane & 15;

    // XCD-aware bijective swizzle: 512 blocks, chunk = 64 per XCD.
    const int GX = 8;                        // gridDim.x
    const int orig = blockIdx.y * GX + blockIdx.x;
    const int swz  = (orig & 7) * 64 + (orig >> 3);
    const int m0 = (swz / GX) * 64;
    const int n0 = (swz % GX) * 128;
    const int wm = (wave >> 1) * 32;
    const int wn = (wave & 1) * 64;

    float4v acc[2][4];
#pragma unroll
    for (int i = 0; i < 2; i++)
#pragma unroll
        for (int j = 0; j < 4; j++) acc[i][j] = (float4v){0.f, 0.f, 0.f, 0.f};

    const int NT = 32;                       // K / 32
#define PROJ_STAGE(tt, bufi)                                                  \
    {                                                                         \
        const int k1 = (tt) * 32;                                             \
        unsigned short* Ab = smem + (bufi) * 2048;                            \
        unsigned short* Bb = smem + 6144 + (bufi) * 4096;                     \
        async16(A + (size_t)(m0 + (tid >> 2)) * K + k1 + (tid & 3) * 8,       \
                (const char*)Ab + tid * 16);                                  \
        _Pragma("unroll")                                                     \
        for (int rd = 0; rd < 2; rd++) {                                      \
            const int p = rd * 256 + tid;                                     \
            async16(Bt + (size_t)(n0 + (p >> 2)) * K + k1 + (p & 3) * 8,      \
                    (const char*)Bb + p * 16);                                \
        }                                                                     \
    }

    PROJ_STAGE(0, 0);
    PROJ_STAGE(1, 1);

    int rb = 0;
    for (int t = 0; t < NT; t++) {
        if (t + 1 < NT) asm volatile("s_waitcnt vmcnt(3)" ::: "memory");
        else            asm volatile("s_waitcnt vmcnt(0)" ::: "memory");
        __builtin_amdgcn_s_barrier();
        __builtin_amdgcn_sched_barrier(0);

        if (t + 2 < NT) {
            const int sbi = (rb + 2 >= 3) ? rb - 1 : rb + 2;
            PROJ_STAGE(t + 2, sbi);
        }

        const unsigned short* Ar = smem + rb * 2048;
        const unsigned short* Br = smem + 6144 + rb * 4096;
        short8 af[2], bf[4];
#pragma unroll
        for (int mt = 0; mt < 2; mt++)
            af[mt] = *(const short8*)(Ar + (wm + mt * 16 + l16) * 32 + quad * 8);
#pragma unroll
        for (int nt = 0; nt < 4; nt++)
            bf[nt] = *(const short8*)(Br + (wn + nt * 16 + l16) * 32 + quad * 8);
#pragma unroll
        for (int mt = 0; mt < 2; mt++)
#pragma unroll
            for (int nt = 0; nt < 4; nt++)
                acc[mt][nt] = __builtin_amdgcn_mfma_f32_16x16x32_bf16(
                    af[mt], bf[nt], acc[mt][nt], 0, 0, 0);

        rb = (rb + 1 == 3) ? 0 : rb + 1;
    }
#undef PROJ_STAGE

#pragma unroll
    for (int nt = 0; nt < 4; nt++) {
        const int col = n0 + wn + nt * 16 + l16;
        const float bia = bias[col];
#pragma unroll
        for (int mt = 0; mt < 2; mt++) {
            const int rowb = m0 + wm + mt * 16 + quad * 4;
#pragma unroll
            for (int r = 0; r < 4; r++)
                out_f[(size_t)(rowb + r) * N + col] = acc[mt][nt][r] + bia;
        }
    }
}

// ---------------------------------------------------------------------------
// Attention v6p (R20): 3-buffer counted-vmcnt staging.  1024 blocks x 256
// thr (4 waves, 16 q each).  Prologue stages chunks 0,1; iteration c issues
// stage(c+2) into buf (c+2)%3; barrier = s_waitcnt vmcnt(4) + raw s_barrier
// + sched_barrier(0).  bh = bx&31 pins heads to XCDs; qb = 31-(bx>>5)
// dispatches heavy first.
// ---------------------------------------------------------------------------
__global__ __launch_bounds__(256) void attn6p_kernel(
    const unsigned short* __restrict__ Q,    // [bh][s][64] pre-scaled
    const unsigned short* __restrict__ Kp,   // [bh][32][4][2][64][8]
    const unsigned short* __restrict__ Vp,   // [bh][32][4][2][64][8]
    unsigned short* __restrict__ ctx)        // [B, S, H*64]
{
    __shared__ unsigned short lds[3][8192];  // [buf][K 0..4095 | V 4096..8191]

    const int tid  = threadIdx.x;
    const int lane = tid & 63;
    const int wave = tid >> 6;
    const int quad = lane >> 4;
    const int l16  = lane & 15;

    const int bx = blockIdx.x;
    const int bh = bx & 31;
    const int qb = 31 - (bx >> 5);
    const int q0 = qb * 64 + wave * 16;
    const int nch = qb + 1;

    const size_t baseQ = (size_t)bh * S_LEN * HDIM;
    const unsigned short* kb_ = Kp + (size_t)bh * 32 * 4096;
    const unsigned short* vb_ = Vp + (size_t)bh * 32 * 4096;

    short8 qf[2];
#pragma unroll
    for (int h = 0; h < 2; h++)
        qf[h] = *(const short8*)(Q + baseQ + (size_t)(q0 + l16) * HDIM
                                 + h * 32 + quad * 8);

    float4v o[4];
#pragma unroll
    for (int nt = 0; nt < 4; nt++) o[nt] = (float4v){0.f, 0.f, 0.f, 0.f};
    float lsa[4] = {0.f, 0.f, 0.f, 0.f};

    // prologue: stage chunks 0 and 1 (4 async16 each per thread)
    {
        unsigned short* sb = &lds[0][0];
        async16(kb_ + tid * 8,        sb + wave * 512);
        async16(kb_ + 2048 + tid * 8, sb + 2048 + wave * 512);
        async16(vb_ + tid * 8,        sb + 4096 + wave * 512);
        async16(vb_ + 2048 + tid * 8, sb + 6144 + wave * 512);
    }
    if (nch > 1) {
        const unsigned short* kc = kb_ + 4096;
        const unsigned short* vc = vb_ + 4096;
        unsigned short* sb = &lds[1][0];
        async16(kc + tid * 8,        sb + wave * 512);
        async16(kc + 2048 + tid * 8, sb + 2048 + wave * 512);
        async16(vc + tid * 8,        sb + 4096 + wave * 512);
        async16(vc + 2048 + tid * 8, sb + 6144 + wave * 512);
    }

    int rb = 0;    // read-buffer index = c % 3
    for (int c = 0; c < nch; c++) {
        // stage(c) must be landed for ALL waves; stage(c+1) stays in flight.
        if (c + 1 < nch) asm volatile("s_waitcnt vmcnt(4)" ::: "memory");
        else             asm volatile("s_waitcnt vmcnt(0)" ::: "memory");
        __builtin_amdgcn_s_barrier();
        __builtin_amdgcn_sched_barrier(0);

        const unsigned short* lb = &lds[rb][0];

        // K fragments: linear conflict-free ds_read_b128
        short8 kf[4][2];
#pragma unroll
        for (int kt = 0; kt < 4; kt++)
#pragma unroll
            for (int h = 0; h < 2; h++)
                kf[kt][h] = *(const short8*)(lb + ((kt * 2 + h) * 64 + lane) * 8);

        // stage chunk c+2 into buf (c+2)%3 (lands by barrier of c+2)
        if (c + 2 < nch) {
            const int sbi = (rb + 2 >= 3) ? rb - 1 : rb + 2;
            const unsigned short* kc = kb_ + (size_t)(c + 2) * 4096;
            const unsigned short* vc = vb_ + (size_t)(c + 2) * 4096;
            unsigned short* sb = &lds[sbi][0];
            async16(kc + tid * 8,        sb + wave * 512);
            async16(kc + 2048 + tid * 8, sb + 2048 + wave * 512);
            async16(vc + tid * 8,        sb + 4096 + wave * 512);
            async16(vc + 2048 + tid * 8, sb + 6144 + wave * 512);
        }

        float4v st[4];
#pragma unroll
        for (int kt = 0; kt < 4; kt++) {
            st[kt] = __builtin_amdgcn_mfma_f32_16x16x32_bf16(
                kf[kt][0], qf[0], (float4v){0.f, 0.f, 0.f, 0.f}, 0, 0, 0);
            st[kt] = __builtin_amdgcn_mfma_f32_16x16x32_bf16(
                kf[kt][1], qf[1], st[kt], 0, 0, 0);
        }

        // V fragments issue while the softmax VALU below runs
        short8 vf[4][2];
#pragma unroll
        for (int nt = 0; nt < 4; nt++)
#pragma unroll
            for (int kk = 0; kk < 2; kk++)
                vf[nt][kk] = *(const short8*)(lb + 4096
                                              + ((nt * 2 + kk) * 64 + lane) * 8);

        const bool lastc = (c == nch - 1);
        const int kb0 = c * 64;
        const int qpos = q0 + l16;
        float p[4][4];
#pragma unroll
        for (int kt = 0; kt < 4; kt++)
#pragma unroll
            for (int r = 0; r < 4; r++) {
                float x = st[kt][r];
                if (lastc) {
                    int kpos = kb0 + kt * 16 + quad * 4 + r;
                    x = (kpos <= qpos) ? x : -1e30f;
                }
                p[kt][r] = __builtin_amdgcn_exp2f(x);
                lsa[kt] += p[kt][r];     // 4 parallel chains
            }

        unsigned pk[4][2];
#pragma unroll
        for (int kt = 0; kt < 4; kt++)
#pragma unroll
            for (int j = 0; j < 2; j++)
                pk[kt][j] = __builtin_amdgcn_perm(
                    fbits_rn(p[kt][2 * j + 1]), fbits_rn(p[kt][2 * j]),
                    0x07060302);
        union { unsigned u[4]; short8 s; } pf[2];
#pragma unroll
        for (int kk = 0; kk < 2; kk++)
#pragma unroll
            for (int pp = 0; pp < 4; pp++)
                pf[kk].u[pp] = pk[kk * 2 + (pp >> 1)][pp & 1];

#pragma unroll
        for (int nt = 0; nt < 4; nt++) {
            o[nt] = __builtin_amdgcn_mfma_f32_16x16x32_bf16(
                pf[0].s, vf[nt][0], o[nt], 0, 0, 0);
            o[nt] = __builtin_amdgcn_mfma_f32_16x16x32_bf16(
                pf[1].s, vf[nt][1], o[nt], 0, 0, 0);
        }

        rb = (rb + 1 == 3) ? 0 : rb + 1;
    }

    float l = (lsa[0] + lsa[1]) + (lsa[2] + lsa[3]);
    l += __shfl_xor(l, 16, 64);
    l += __shfl_xor(l, 32, 64);
    const float linv = 1.f / l;
    float lr[4];
#pragma unroll
    for (int r = 0; r < 4; r++) lr[r] = __shfl(linv, quad * 4 + r, 64);

    const int b = bh >> 4, h = bh & 15;
#pragma unroll
    for (int r = 0; r < 4; r++) {
        const int s = q0 + quad * 4 + r;
        const size_t off = ((size_t)(b * S_LEN + s)) * DMODEL + h * HDIM;
#pragma unroll
        for (int nt = 0; nt < 4; nt++)
            ctx[off + nt * 16 + l16] = f2bf(o[nt][r] * lr[r]);
    }
}

extern "C" void kernel_launch(void* const* d_in, const int* in_sizes, int n_in,
                              void* d_out, int out_size, void* d_ws, size_t ws_size,
                              hipStream_t stream) {
    const float* x     = (const float*)d_in[0];
    const float* Wqkv  = (const float*)d_in[1];
    const float* bqkv  = (const float*)d_in[2];
    const float* Wproj = (const float*)d_in[3];
    const float* bproj = (const float*)d_in[4];
    float* out = (float*)d_out;

    const int M  = 2 * S_LEN;     // 4096
    const int N1 = 3 * DMODEL;    // 3072
    const int K  = DMODEL;        // 1024

    unsigned short* x_bf    = (unsigned short*)d_ws;
    unsigned short* wqkv_t  = x_bf   + (size_t)M * K;
    unsigned short* wproj_t = wqkv_t + (size_t)K * N1;
    unsigned short* q_bf    = wproj_t + (size_t)K * DMODEL;
    unsigned short* kp_bf   = q_bf   + (size_t)M * DMODEL;
    unsigned short* vp_bf   = kp_bf  + (size_t)M * DMODEL;  // Vp fragment-major
    unsigned short* ctx_bf  = vp_bf  + (size_t)M * DMODEL;

    prep_kernel<<<5120, 256, 0, stream>>>(x, x_bf, Wqkv, Wproj,
                                          wqkv_t, wproj_t);

    dim3 g1(N1 / 128, M / 128);   // 24 x 32
    gemm_qkv_kernel<<<g1, 256, 0, stream>>>(x_bf, wqkv_t, bqkv,
                                            q_bf, kp_bf, vp_bf, M, N1, K);

    attn6p_kernel<<<1024, 256, 0, stream>>>(q_bf, kp_bf, vp_bf, ctx_bf);

    dim3 g3(DMODEL / 128, M / 64);   // 8 x 64
    gemm_proj_kernel<<<g3, 256, 0, stream>>>(ctx_bf, wproj_t, bproj, out,
                                             M, DMODEL, K);
}